// Round 5
// baseline (9325.407 us; speedup 1.0000x reference)
//
#include <hip/hip_runtime.h>

#define N_ALL 20000
#define NPCD  5000
#define NRGB  15000
#define CPCD  32
#define CRGB  128
#define CF    160
#define NA    4096
#define SANS  32
#define NBK   64
#define K1    163
#define K1P   168
#define HD    128
#define FPK   288
#define NSOA  20480   // 2048*10 — pair-SoA padded length for FPS

// ---------------- prep: build xyz(20000x3), SoA copies, feat(20000x160), padded sa_W1(128x168) ----------------
__global__ void prep_kernel(const float* __restrict__ pcd_xyz,
                            const float* __restrict__ pcd_feat,
                            const float* __restrict__ rgb_xyz,
                            const float* __restrict__ rgb_feat,
                            const float* __restrict__ sa_W1,
                            float* __restrict__ xyz,
                            float* __restrict__ feat,
                            float* __restrict__ W1p,
                            float* __restrict__ xsoa,
                            float* __restrict__ ysoa,
                            float* __restrict__ zsoa) {
  const int TOT = N_ALL*CF + N_ALL*3 + HD*K1P + NSOA;
  for (int id = blockIdx.x*blockDim.x + threadIdx.x; id < TOT; id += gridDim.x*blockDim.x) {
    if (id < N_ALL*CF) {
      int r = id / CF, c = id - r*CF;
      float v = 0.0f;
      if (r < NPCD) { if (c < CPCD) v = pcd_feat[r*CPCD + c]; }
      else          { if (c >= CPCD) v = rgb_feat[(c - CPCD)*NRGB + (r - NPCD)]; }
      feat[id] = v;
    } else if (id < N_ALL*CF + N_ALL*3) {
      int e = id - N_ALL*CF;
      xyz[e] = (e < NPCD*3) ? pcd_xyz[e] : rgb_xyz[e - NPCD*3];
    } else if (id < N_ALL*CF + N_ALL*3 + HD*K1P) {
      int e = id - (N_ALL*CF + N_ALL*3);
      int o = e / K1P, c = e - o*K1P;
      W1p[e] = (c < K1) ? sa_W1[o*K1 + c] : 0.0f;
    } else {
      int p = id - (N_ALL*CF + N_ALL*3 + HD*K1P);  // 0..NSOA-1
      float vx = 0.0f, vy = 0.0f, vz = 0.0f;
      if (p < NPCD)      { vx = pcd_xyz[3*p]; vy = pcd_xyz[3*p+1]; vz = pcd_xyz[3*p+2]; }
      else if (p < N_ALL){ int q = p - NPCD; vx = rgb_xyz[3*q]; vy = rgb_xyz[3*q+1]; vz = rgb_xyz[3*q+2]; }
      xsoa[p] = vx; ysoa[p] = vy; zsoa[p] = vz;
    }
  }
}

// ---------------- FPS: single block; x,y resident in LDS (160000 B), z + min-dists in registers ----------------
// Rounds 2-4: the allocator pins this kernel at 64 VGPRs and re-loads any larger working set
// from L2 every iteration (remat or scratch-spill — identical cost, invisible in HBM counters).
// Fix: stop fighting it. x,y live in LDS packed per point-pair {x2k,x2k+1,y2k,y2k+1} -> one
// ds_read_b128 per pair (~0.3us/iter of LDS BW); z(20)+ds(20) stay in registers within the
// 64-VGPR budget. Out-of-range pairs clamp to pair 9999 (broadcast read, free); their ds
// sentinel is -1 so they never win the argmax.
__global__ void __launch_bounds__(1024)
fps_kernel(const float* __restrict__ xsoa,
           const float* __restrict__ ysoa,
           const float* __restrict__ zsoa,
           float* __restrict__ axyz) {
  #pragma clang fp contract(off)
  __shared__ float xy4[40000];        // 160000 B
  __shared__ float wred[2][16];
  __shared__ unsigned slot[2];
  const int t = threadIdx.x, lane = t & 63, wv = t >> 6;
  // fill LDS: pair k -> {x2k, x2k+1, y2k, y2k+1}
  for (int j = 0; j < 20; j++) {
    int m = t + (j << 10);
    if (m < N_ALL) {
      int k4 = (m >> 1) << 2, e = m & 1;
      xy4[k4 + e]     = xsoa[m];
      xy4[k4 + 2 + e] = ysoa[m];
    }
  }
  if (t == 0) { slot[0] = 0xFFFFFFFFu; slot[1] = 0xFFFFFFFFu; }
  // z coords + min-dists in registers; thread t owns points p = 2t + 2048*j (+0/1)
  float zs[20]; float2 ds2[10];
  #pragma unroll
  for (int j = 0; j < 10; j++) {
    int p = (t << 1) + (j << 11);
    float2 vz = *(const float2*)(zsoa + p);
    zs[2*j] = vz.x; zs[2*j+1] = vz.y;
    ds2[j].x = (p     < N_ALL) ? 1e10f : -1.0f;   // pads never win (real dists >= 0)
    ds2[j].y = (p + 1 < N_ALL) ? 1e10f : -1.0f;
  }
  float cx = xsoa[0], cy = ysoa[0], cz = zsoa[0];
  if (t == 0) { axyz[0] = cx; axyz[1] = cy; axyz[2] = cz; }
  __syncthreads();
  for (int it = 1; it < NA; ++it) {
    const int par = it & 1;
    float mx0 = -1e30f, mx1 = -1e30f;
    #pragma unroll
    for (int j = 0; j < 10; j++) {
      int k = t + (j << 10);
      int kc = (k < 10000) ? k : 9999;          // clamp: only j==9 tail; values masked by ds=-1
      const float4 v = *(const float4*)(xy4 + (kc << 2));   // ds_read_b128
      float dx0 = v.x - cx, dx1 = v.y - cx;
      float dy0 = v.z - cy, dy1 = v.w - cy;
      float dz0 = zs[2*j] - cz, dz1 = zs[2*j+1] - cz;
      float d0 = (dx0*dx0 + dy0*dy0) + dz0*dz0;   // plain f32, no contraction (matches numpy)
      float d1 = (dx1*dx1 + dy1*dy1) + dz1*dz1;
      float n0 = fminf(ds2[j].x, d0);
      float n1 = fminf(ds2[j].y, d1);
      ds2[j].x = n0; ds2[j].y = n1;
      mx0 = fmaxf(mx0, n0); mx1 = fmaxf(mx1, n1);
    }
    float tmax = fmaxf(mx0, mx1);
    // wave reduce (value only)
    float wm = tmax;
    #pragma unroll
    for (int off = 1; off < 64; off <<= 1) wm = fmaxf(wm, __shfl_xor(wm, off));
    if (lane == 0) wred[par][wv] = wm;
    __syncthreads();
    float M = wred[par][0];
    #pragma unroll
    for (int w = 1; w < 16; w++) M = fmaxf(M, wred[par][w]);
    if (t == 0) slot[par ^ 1] = 0xFFFFFFFFu;     // reset other slot for next iter
    // rare branch: threads holding the max scan for their lowest matching global index
    if (tmax == M) {
      unsigned best = 0xFFFFFFFFu;
      #pragma unroll
      for (int j = 9; j >= 0; j--) {
        unsigned p = (unsigned)((t << 1) + (j << 11));
        if (ds2[j].y == M) best = p + 1;
        if (ds2[j].x == M) best = p;             // checked after .y: lowest index wins
      }
      atomicMin(&slot[par], best);               // exact lowest-index tie-break
    }
    __syncthreads();
    unsigned gi = slot[par];
    unsigned kg4 = (gi >> 1) << 2, ge = gi & 1;
    cx = xy4[kg4 + ge];                          // broadcast LDS reads
    cy = xy4[kg4 + 2 + ge];
    cz = zsoa[gi];                               // broadcast L2 read
    if (t == 0) { axyz[3*it] = cx; axyz[3*it+1] = cy; axyz[3*it+2] = cz; }
  }
}

// ---------------- ball query (wave per center): first K smallest indices with d2 < r2 ----------------
__global__ void sa_bq_kernel(const float* __restrict__ xyz,
                             const float* __restrict__ axyz,
                             int* __restrict__ nb) {
  #pragma clang fp contract(off)
  int wv = threadIdx.x >> 6, lane = threadIdx.x & 63;
  int a = blockIdx.x*4 + wv;
  float ax = axyz[3*a], ay = axyz[3*a+1], az = axyz[3*a+2];
  int cnt = 0, my = 0;
  for (int base = 0; base < N_ALL; base += 64) {
    int p = base + lane;
    bool in = false;
    if (p < N_ALL) {
      float dx = ax - xyz[3*p], dy = ay - xyz[3*p+1], dz = az - xyz[3*p+2];
      float d2 = (dx*dx + dy*dy) + dz*dz;
      in = d2 < 0.01f;
    }
    unsigned long long mask = __ballot(in);
    while (mask && cnt < SANS) {
      int b = __builtin_ctzll(mask);
      mask &= mask - 1;
      if (cnt == lane) my = base + b;
      cnt++;
    }
    if (cnt >= SANS) break;
  }
  int f0 = __shfl(my, 0);
  if (lane < SANS) nb[a*SANS + lane] = (lane < cnt) ? my : f0;
}

__global__ void det_bq_kernel(const float* __restrict__ pxyz,
                              int* __restrict__ nb) {
  #pragma clang fp contract(off)
  int wv = threadIdx.x >> 6, lane = threadIdx.x & 63;
  int i = blockIdx.x*4 + wv;
  float ax = pxyz[3*i], ay = pxyz[3*i+1], az = pxyz[3*i+2];
  int cnt = 0, my = 0;
  for (int base = 0; base < NPCD; base += 64) {
    int p = base + lane;
    bool in = false;
    if (p < NPCD) {
      float dx = ax - pxyz[3*p], dy = ay - pxyz[3*p+1], dz = az - pxyz[3*p+2];
      float d2 = (dx*dx + dy*dy) + dz*dz;
      in = d2 < 0.04f;
    }
    unsigned long long mask = __ballot(in);
    while (mask && cnt < NBK) {
      int b = __builtin_ctzll(mask);
      mask &= mask - 1;
      if (cnt == lane) my = base + b;
      cnt++;
    }
    if (cnt >= NBK) break;
  }
  int f0 = __shfl(my, 0);
  nb[i*NBK + lane] = (lane < cnt) ? my : f0;
}

// ---------------- SA: gather g(32x163) -> 3x MLP(128) -> maxpool, one anchor per block ----------------
__global__ void __launch_bounds__(128) sa_mlp_kernel(const float* __restrict__ xyz,
                                                     const float* __restrict__ feat,
                                                     const float* __restrict__ axyz,
                                                     const int* __restrict__ nb,
                                                     const float* __restrict__ W1p,
                                                     const float* __restrict__ b1,
                                                     const float* __restrict__ W2,
                                                     const float* __restrict__ b2,
                                                     const float* __restrict__ W3,
                                                     const float* __restrict__ b3,
                                                     float* __restrict__ sa_feat) {
  __shared__ float g[SANS*K1P];     // 21504 B, reused as h2
  __shared__ float h1[SANS*HD];     // 16384 B
  __shared__ int nbs[SANS];
  int a = blockIdx.x, tid = threadIdx.x;
  if (tid < SANS) nbs[tid] = nb[a*SANS + tid];
  float ax = axyz[3*a], ay = axyz[3*a+1], az = axyz[3*a+2];
  __syncthreads();
  for (int e = tid; e < SANS*K1P; e += 128) {
    int s = e / K1P, c = e - s*K1P;
    float v = 0.0f;
    int p = nbs[s];
    if (c < 3) {
      float pc  = xyz[3*p + c];
      float acx = (c == 0) ? ax : ((c == 1) ? ay : az);
      v = (pc - acx) / 0.1f;
    } else if (c < K1) {
      v = feat[p*CF + (c - 3)];
    }
    g[e] = v;
  }
  __syncthreads();
  const int o = tid;
  float acc[SANS];
  // layer 1: K = 168 (zero padded)
  #pragma unroll
  for (int s = 0; s < SANS; s++) acc[s] = b1[o];
  for (int kc = 0; kc < 21; kc++) {
    const float4* wp = (const float4*)(W1p + o*K1P + kc*8);
    float4 w0 = wp[0], w1 = wp[1];
    #pragma unroll
    for (int s = 0; s < SANS; s++) {
      const float4* gp = (const float4*)(g + s*K1P + kc*8);
      float4 g0 = gp[0], g1 = gp[1];
      acc[s] += w0.x*g0.x + w0.y*g0.y + w0.z*g0.z + w0.w*g0.w
              + w1.x*g1.x + w1.y*g1.y + w1.z*g1.z + w1.w*g1.w;
    }
  }
  #pragma unroll
  for (int s = 0; s < SANS; s++) h1[s*HD + o] = fmaxf(acc[s], 0.0f);
  __syncthreads();
  // layer 2: K = 128, write h2 into g buffer
  #pragma unroll
  for (int s = 0; s < SANS; s++) acc[s] = b2[o];
  for (int kc = 0; kc < 16; kc++) {
    const float4* wp = (const float4*)(W2 + o*HD + kc*8);
    float4 w0 = wp[0], w1 = wp[1];
    #pragma unroll
    for (int s = 0; s < SANS; s++) {
      const float4* gp = (const float4*)(h1 + s*HD + kc*8);
      float4 g0 = gp[0], g1 = gp[1];
      acc[s] += w0.x*g0.x + w0.y*g0.y + w0.z*g0.z + w0.w*g0.w
              + w1.x*g1.x + w1.y*g1.y + w1.z*g1.z + w1.w*g1.w;
    }
  }
  float* h2 = g;
  #pragma unroll
  for (int s = 0; s < SANS; s++) h2[s*HD + o] = fmaxf(acc[s], 0.0f);
  __syncthreads();
  // layer 3 + max pool
  #pragma unroll
  for (int s = 0; s < SANS; s++) acc[s] = b3[o];
  for (int kc = 0; kc < 16; kc++) {
    const float4* wp = (const float4*)(W3 + o*HD + kc*8);
    float4 w0 = wp[0], w1 = wp[1];
    #pragma unroll
    for (int s = 0; s < SANS; s++) {
      const float4* gp = (const float4*)(h2 + s*HD + kc*8);
      float4 g0 = gp[0], g1 = gp[1];
      acc[s] += w0.x*g0.x + w0.y*g0.y + w0.z*g0.z + w0.w*g0.w
              + w1.x*g1.x + w1.y*g1.y + w1.z*g1.z + w1.w*g1.w;
    }
  }
  float m = 0.0f;
  #pragma unroll
  for (int s = 0; s < SANS; s++) m = fmaxf(m, fmaxf(acc[s], 0.0f));
  sa_feat[a*HD + o] = m;
}

// ---------------- 3-NN interp (first 5000 points only) + build F row [interp(128)|feat(160)] ----------------
#define INSERT3(v) { if ((v) < t0){ t2=t1; t1=t0; t0=(v);} \
                     else if ((v) < t1){ t2=t1; t1=(v);} \
                     else if ((v) < t2){ t2=(v);} }

__global__ void nn_interp_kernel(const float* __restrict__ xyz,
                                 const float* __restrict__ feat,
                                 const float* __restrict__ axyz,
                                 const float* __restrict__ sa_feat,
                                 float* __restrict__ F) {
  #pragma clang fp contract(off)
  int wv = threadIdx.x >> 6, lane = threadIdx.x & 63;
  int p = blockIdx.x*4 + wv;
  float px = xyz[3*p], py = xyz[3*p+1], pz = xyz[3*p+2];
  unsigned long long t0 = ~0ull, t1 = ~0ull, t2 = ~0ull;
  for (int j = 0; j < 64; j++) {
    int a = lane + (j << 6);
    float dx = px - axyz[3*a], dy = py - axyz[3*a+1], dz = pz - axyz[3*a+2];
    float d2 = (dx*dx + dy*dy) + dz*dz;
    unsigned long long pk = ((unsigned long long)__float_as_uint(d2) << 32) | (unsigned)a;
    INSERT3(pk);
  }
  #pragma unroll
  for (int off = 1; off < 64; off <<= 1) {
    unsigned long long b0 = __shfl_xor(t0, off);
    unsigned long long b1 = __shfl_xor(t1, off);
    unsigned long long b2 = __shfl_xor(t2, off);
    INSERT3(b0); INSERT3(b1); INSERT3(b2);
  }
  float d0 = __uint_as_float((unsigned)(t0 >> 32));
  float d1 = __uint_as_float((unsigned)(t1 >> 32));
  float d2v = __uint_as_float((unsigned)(t2 >> 32));
  int a0 = (int)(t0 & 0xFFFFFFFFull), a1 = (int)(t1 & 0xFFFFFFFFull), a2 = (int)(t2 & 0xFFFFFFFFull);
  float w0 = 1.0f/(d0 + 1e-8f), w1 = 1.0f/(d1 + 1e-8f), w2 = 1.0f/(d2v + 1e-8f);
  float wsum = w0 + w1 + w2;
  w0 /= wsum; w1 /= wsum; w2 /= wsum;
  const float* s0 = sa_feat + a0*HD;
  const float* s1 = sa_feat + a1*HD;
  const float* s2 = sa_feat + a2*HD;
  float* Fr = F + p*FPK;
  Fr[lane]      = w0*s0[lane]    + w1*s1[lane]    + w2*s2[lane];
  Fr[lane + 64] = w0*s0[lane+64] + w1*s1[lane+64] + w2*s2[lane+64];
  const float* fr = feat + p*CF;
  Fr[HD + lane]      = fr[lane];
  Fr[HD + lane + 64] = fr[lane + 64];
  if (lane < 32) Fr[HD + 128 + lane] = fr[128 + lane];
}

// ---------------- FP layer 1: (5000x288)x(288->128), relu ----------------
__global__ void __launch_bounds__(128) fp1_kernel(const float* __restrict__ F,
                                                  const float* __restrict__ W,
                                                  const float* __restrict__ b,
                                                  float* __restrict__ H) {
  __shared__ float A[32*FPK];
  int base = blockIdx.x*32, tid = threadIdx.x;
  for (int e = tid; e < 32*FPK; e += 128) {
    int r = e / FPK; int gr = base + r;
    A[e] = (gr < NPCD) ? F[gr*FPK + (e - r*FPK)] : 0.0f;
  }
  __syncthreads();
  const int o = tid;
  float acc[32];
  #pragma unroll
  for (int r = 0; r < 32; r++) acc[r] = b[o];
  for (int kc = 0; kc < 36; kc++) {
    const float4* wp = (const float4*)(W + o*FPK + kc*8);
    float4 w0 = wp[0], w1 = wp[1];
    #pragma unroll
    for (int r = 0; r < 32; r++) {
      const float4* ap = (const float4*)(A + r*FPK + kc*8);
      float4 a0 = ap[0], a1 = ap[1];
      acc[r] += w0.x*a0.x + w0.y*a0.y + w0.z*a0.z + w0.w*a0.w
              + w1.x*a1.x + w1.y*a1.y + w1.z*a1.z + w1.w*a1.w;
    }
  }
  #pragma unroll
  for (int r = 0; r < 32; r++) {
    int gr = base + r;
    if (gr < NPCD) H[gr*HD + o] = fmaxf(acc[r], 0.0f);
  }
}

// ---------------- FP layer 2: (5000x128)x(128->32), relu ----------------
__global__ void __launch_bounds__(256) fp2_kernel(const float* __restrict__ Hin,
                                                  const float* __restrict__ W,
                                                  const float* __restrict__ b,
                                                  float* __restrict__ fpf,
                                                  unsigned* __restrict__ gmax) {
  if (blockIdx.x == 0 && threadIdx.x == 0) *gmax = 0u;  // init for the gmax kernel that follows
  __shared__ float A[32*HD];
  int base = blockIdx.x*32, tid = threadIdx.x;
  for (int e = tid; e < 32*HD; e += 256) {
    int r = e >> 7; int gr = base + r;
    A[e] = (gr < NPCD) ? Hin[gr*HD + (e & 127)] : 0.0f;
  }
  __syncthreads();
  int o = tid & 31, rg = tid >> 5;
  float acc[4];
  #pragma unroll
  for (int j = 0; j < 4; j++) acc[j] = b[o];
  for (int kc = 0; kc < 16; kc++) {
    const float4* wp = (const float4*)(W + o*HD + kc*8);
    float4 w0 = wp[0], w1 = wp[1];
    #pragma unroll
    for (int j = 0; j < 4; j++) {
      int r = rg + (j << 3);
      const float4* ap = (const float4*)(A + r*HD + kc*8);
      float4 a0 = ap[0], a1 = ap[1];
      acc[j] += w0.x*a0.x + w0.y*a0.y + w0.z*a0.z + w0.w*a0.w
              + w1.x*a1.x + w1.y*a1.y + w1.z*a1.z + w1.w*a1.w;
    }
  }
  #pragma unroll
  for (int j = 0; j < 4; j++) {
    int gr = base + rg + (j << 3);
    if (gr < NPCD) fpf[gr*CPCD + o] = fmaxf(acc[j], 0.0f);
  }
}

// ---------------- global max of fp_feat (all >= 0) ----------------
__global__ void gmax_kernel(const float* __restrict__ fpf, unsigned* __restrict__ gmax) {
  int id = blockIdx.x*256 + threadIdx.x;
  float m = (id < NPCD*CPCD) ? fpf[id] : 0.0f;
  #pragma unroll
  for (int off = 1; off < 64; off <<= 1) m = fmaxf(m, __shfl_xor(m, off));
  if ((threadIdx.x & 63) == 0) atomicMax(gmax, __float_as_uint(m));
}

// ---------------- detection scores (wave per point) ----------------
__global__ void det_score_kernel(const float* __restrict__ fpf,
                                 const int* __restrict__ nbd,
                                 const unsigned* __restrict__ gmax,
                                 float* __restrict__ outs) {
  int wv = threadIdx.x >> 6, lane = threadIdx.x & 63;
  int i = blockIdx.x*4 + wv;
  float g = __uint_as_float(*gmax);
  float scale = 1.0f / (g + 1e-6f);
  int c = lane & 31, h = lane >> 5;
  float sum = 0.0f;
  const int* nbr = nbd + i*NBK + h*32;
  for (int k = 0; k < 32; k++) {
    int idx = nbr[k];
    sum += fpf[idx*CPCD + c];
  }
  sum += __shfl_xor(sum, 32);
  float mean = (sum * scale) * 0.015625f;   // /64 exact
  float fi = fpf[i*CPCD + c] * scale;
  float x = fi - mean;
  float lm = fmaxf(x, 0.0f) + log1pf(expf(-fabsf(x)));  // softplus = logaddexp(x,0)
  float dm = fi;
  #pragma unroll
  for (int off = 1; off < 64; off <<= 1) dm = fmaxf(dm, __shfl_xor(dm, off));
  float dw = fi / (1e-6f + dm);
  float pr = lm * dw;
  #pragma unroll
  for (int off = 1; off < 64; off <<= 1) pr = fmaxf(pr, __shfl_xor(pr, off));
  if (lane == 0) outs[i] = pr;
}

// ---------------- outputs: pcd_xyz copy + normalized vote_features ----------------
__global__ void vote_out_kernel(const float* __restrict__ pcd_xyz,
                                const float* __restrict__ fpf,
                                float* __restrict__ dout) {
  int id = blockIdx.x*256 + threadIdx.x;
  if (id < NPCD*3) dout[id] = pcd_xyz[id];
  int r = id - NPCD*3;
  if (r >= 0 && r < NPCD) {
    float ss = 0.0f;
    const float* fr = fpf + r*CPCD;
    #pragma unroll
    for (int cc = 0; cc < CPCD; cc++) ss += fr[cc]*fr[cc];
    float nrm = fmaxf(sqrtf(ss), 1e-12f);
    float* vf = dout + NPCD*3 + NPCD + r*CPCD;
    #pragma unroll
    for (int cc = 0; cc < CPCD; cc++) vf[cc] = fr[cc] / nrm;
  }
}

extern "C" void kernel_launch(void* const* d_in, const int* in_sizes, int n_in,
                              void* d_out, int out_size, void* d_ws, size_t ws_size,
                              hipStream_t stream) {
  const float* pcd_xyz      = (const float*)d_in[0];
  const float* pcd_features = (const float*)d_in[1];
  const float* rgb_xyz      = (const float*)d_in[2];
  const float* rgb_features = (const float*)d_in[3];
  const float* sa_W1 = (const float*)d_in[4];
  const float* sa_b1 = (const float*)d_in[5];
  const float* sa_W2 = (const float*)d_in[6];
  const float* sa_b2 = (const float*)d_in[7];
  const float* sa_W3 = (const float*)d_in[8];
  const float* sa_b3 = (const float*)d_in[9];
  const float* fp_W1 = (const float*)d_in[10];
  const float* fp_b1 = (const float*)d_in[11];
  const float* fp_W2 = (const float*)d_in[12];
  const float* fp_b2 = (const float*)d_in[13];
  float* out = (float*)d_out;

  float* xyz  = (float*)d_ws;            // 60000
  float* feat = xyz  + 60000;            // 3,200,000
  float* W1p  = feat + 3200000;          // 21,504
  float* axyz = W1p  + 21504;            // 12,288
  float* saf  = axyz + 12288;            // 524,288
  float* F    = saf  + 524288;           // 1,440,000
  float* Hb   = F    + 1440000;          // 640,000
  float* fpf  = Hb   + 640000;           // 160,000
  int*   fidx = (int*)(fpf + 160000);    // 4096 (reserved, unused)
  int*   nbsa = fidx + 4096;             // 131,072
  int*   nbdet= nbsa + 131072;           // 320,000
  unsigned* gmaxp = (unsigned*)(nbdet + 320000);  // 1
  float* xsoa = (float*)(gmaxp + 1);     // 20480
  float* ysoa = xsoa + NSOA;             // 20480
  float* zsoa = ysoa + NSOA;             // 20480

  prep_kernel<<<2048, 256, 0, stream>>>(pcd_xyz, pcd_features, rgb_xyz, rgb_features,
                                        sa_W1, xyz, feat, W1p, xsoa, ysoa, zsoa);
  fps_kernel<<<1, 1024, 0, stream>>>(xsoa, ysoa, zsoa, axyz);
  sa_bq_kernel<<<1024, 256, 0, stream>>>(xyz, axyz, nbsa);
  sa_mlp_kernel<<<4096, 128, 0, stream>>>(xyz, feat, axyz, nbsa, W1p, sa_b1,
                                          sa_W2, sa_b2, sa_W3, sa_b3, saf);
  nn_interp_kernel<<<1250, 256, 0, stream>>>(xyz, feat, axyz, saf, F);
  fp1_kernel<<<157, 128, 0, stream>>>(F, fp_W1, fp_b1, Hb);
  fp2_kernel<<<157, 256, 0, stream>>>(Hb, fp_W2, fp_b2, fpf, gmaxp);
  det_bq_kernel<<<1250, 256, 0, stream>>>(pcd_xyz, nbdet);
  gmax_kernel<<<625, 256, 0, stream>>>(fpf, gmaxp);
  det_score_kernel<<<1250, 256, 0, stream>>>(fpf, nbdet, gmaxp, out + NPCD*3);
  vote_out_kernel<<<79, 256, 0, stream>>>(pcd_xyz, fpf, out);
}

// Round 6
// 8878.069 us; speedup vs baseline: 1.0504x; 1.0504x over previous
//
#include <hip/hip_runtime.h>

#define N_ALL 20000
#define NPCD  5000
#define NRGB  15000
#define CPCD  32
#define CRGB  128
#define CF    160
#define NA    4096
#define SANS  32
#define NBK   64
#define K1    163
#define K1P   168
#define HD    128
#define FPK   288
#define NSOA  20480
#define NCELL 512      // 8x8x8 spatial cells
#define NCH   313      // ceil(20000/64) chunks of sorted points
#define NPTS_PAD 20032 // NCH*64

// ---------------- prep: build xyz, feat, padded sa_W1, SoA copies, zero cell counters ----------------
__global__ void prep_kernel(const float* __restrict__ pcd_xyz,
                            const float* __restrict__ pcd_feat,
                            const float* __restrict__ rgb_xyz,
                            const float* __restrict__ rgb_feat,
                            const float* __restrict__ sa_W1,
                            float* __restrict__ xyz,
                            float* __restrict__ feat,
                            float* __restrict__ W1p,
                            float* __restrict__ xsoa,
                            float* __restrict__ ysoa,
                            float* __restrict__ zsoa,
                            int* __restrict__ cnt) {
  const int TOT = N_ALL*CF + N_ALL*3 + HD*K1P + NSOA + NCELL;
  for (int id = blockIdx.x*blockDim.x + threadIdx.x; id < TOT; id += gridDim.x*blockDim.x) {
    if (id < N_ALL*CF) {
      int r = id / CF, c = id - r*CF;
      float v = 0.0f;
      if (r < NPCD) { if (c < CPCD) v = pcd_feat[r*CPCD + c]; }
      else          { if (c >= CPCD) v = rgb_feat[(c - CPCD)*NRGB + (r - NPCD)]; }
      feat[id] = v;
    } else if (id < N_ALL*CF + N_ALL*3) {
      int e = id - N_ALL*CF;
      xyz[e] = (e < NPCD*3) ? pcd_xyz[e] : rgb_xyz[e - NPCD*3];
    } else if (id < N_ALL*CF + N_ALL*3 + HD*K1P) {
      int e = id - (N_ALL*CF + N_ALL*3);
      int o = e / K1P, c = e - o*K1P;
      W1p[e] = (c < K1) ? sa_W1[o*K1 + c] : 0.0f;
    } else if (id < N_ALL*CF + N_ALL*3 + HD*K1P + NSOA) {
      int p = id - (N_ALL*CF + N_ALL*3 + HD*K1P);
      float vx = 0.0f, vy = 0.0f, vz = 0.0f;
      if (p < NPCD)      { vx = pcd_xyz[3*p]; vy = pcd_xyz[3*p+1]; vz = pcd_xyz[3*p+2]; }
      else if (p < N_ALL){ int q = p - NPCD; vx = rgb_xyz[3*q]; vy = rgb_xyz[3*q+1]; vz = rgb_xyz[3*q+2]; }
      xsoa[p] = vx; ysoa[p] = vy; zsoa[p] = vz;
    } else {
      cnt[id - (N_ALL*CF + N_ALL*3 + HD*K1P + NSOA)] = 0;
    }
  }
}

// ---------------- counting sort into 512 spatial cells ----------------
__global__ void cellcount_kernel(const float* __restrict__ xsoa,
                                 const float* __restrict__ ysoa,
                                 const float* __restrict__ zsoa,
                                 int* __restrict__ cnt, int* __restrict__ cellid) {
  int p = blockIdx.x*256 + threadIdx.x;
  if (p >= N_ALL) return;
  int ix = min((int)(xsoa[p]*8.0f), 7);
  int iy = min((int)(ysoa[p]*8.0f), 7);
  int iz = min((int)(zsoa[p]*8.0f), 7);
  int c = (ix << 6) | (iy << 3) | iz;
  cellid[p] = c;
  atomicAdd(&cnt[c], 1);
}

__global__ void cellscan_kernel(const int* __restrict__ cnt, int* __restrict__ ofs) {
  __shared__ int a[NCELL];
  int t = threadIdx.x;
  a[t] = cnt[t]; __syncthreads();
  for (int off = 1; off < NCELL; off <<= 1) {
    int v = (t >= off) ? a[t-off] : 0;
    __syncthreads();
    a[t] += v;
    __syncthreads();
  }
  ofs[t] = a[t] - cnt[t];   // exclusive prefix
}

__global__ void scatter_kernel(const float* __restrict__ xsoa,
                               const float* __restrict__ ysoa,
                               const float* __restrict__ zsoa,
                               const int* __restrict__ cellid,
                               int* __restrict__ ofs,
                               float4* __restrict__ pts4) {
  int p = blockIdx.x*256 + threadIdx.x;
  if (p < N_ALL) {
    int s = atomicAdd(&ofs[cellid[p]], 1);
    pts4[s] = make_float4(xsoa[p], ysoa[p], zsoa[p], __int_as_float(p));
  } else if (p < NPTS_PAD) {
    pts4[p] = make_float4(1e9f, 1e9f, 1e9f, __int_as_float(0));
  }
}

// per-chunk tight bbox: {lox,loy,loz, packed 3x10-bit extents (conservative, +1/1024 margin)}
__global__ void bbox_kernel(const float4* __restrict__ pts4, float4* __restrict__ bbox4) {
  int c = blockIdx.x, lane = threadIdx.x;
  int i = (c << 6) + lane;
  bool v = i < N_ALL;
  float4 f = pts4[i];
  float lx = v ? f.x : 1e30f, hx = v ? f.x : -1e30f;
  float ly = v ? f.y : 1e30f, hy = v ? f.y : -1e30f;
  float lz = v ? f.z : 1e30f, hz = v ? f.z : -1e30f;
  #pragma unroll
  for (int off = 1; off < 64; off <<= 1) {
    lx = fminf(lx, __shfl_xor(lx, off)); hx = fmaxf(hx, __shfl_xor(hx, off));
    ly = fminf(ly, __shfl_xor(ly, off)); hy = fmaxf(hy, __shfl_xor(hy, off));
    lz = fminf(lz, __shfl_xor(lz, off)); hz = fmaxf(hz, __shfl_xor(hz, off));
  }
  if (lane == 0) {
    unsigned ex = (unsigned)min(1023, (int)((hx - lx)*1024.0f) + 1);
    unsigned ey = (unsigned)min(1023, (int)((hy - ly)*1024.0f) + 1);
    unsigned ez = (unsigned)min(1023, (int)((hz - lz)*1024.0f) + 1);
    unsigned pk = ex | (ey << 10) | (ez << 20);
    bbox4[c] = make_float4(lx, ly, lz, __uint_as_float(pk));
  }
}

// ---------------- FPS: single block, spatially-pruned chunk sweep ----------------
// ds[20000] + chunk bboxes + chunk-max all in LDS (~88 KB); registers hold almost nothing,
// so the allocator (rounds 2-5's enemy) has nothing to spill/remat. Skip rule is exact:
// f32 RN ops are monotone and lb2 uses the identical (x^2+y^2)+z^2 tree as d, so
// d_f32 >= lb2_f32; skip iff lb2 >= cmax leaves every ds unchanged. Tie-break = lowest
// ORIGINAL index among ds==M (orig idx carried in pts4.w), matching jnp.argmax exactly.
__global__ void __launch_bounds__(1024)
fps_kernel(const float4* __restrict__ pts4,
           const float4* __restrict__ bbox4,
           const float* __restrict__ xsoa,
           const float* __restrict__ ysoa,
           const float* __restrict__ zsoa,
           float* __restrict__ axyz) {
  #pragma clang fp contract(off)
  __shared__ float  dsh[NPTS_PAD];     // 80128 B
  __shared__ float4 bbLD[NCH];         //  5008 B
  __shared__ float  cmaxLD[NCH];       //  1252 B
  __shared__ int    actList[NCH];      //  1252 B
  __shared__ float  wredT[5], wredU[16];
  __shared__ int    candC[8];
  __shared__ float4 candB[8];
  __shared__ int    nact, ncand, nw;
  const int t = threadIdx.x, lane = t & 63, wv = t >> 6;

  for (int i = t; i < NPTS_PAD; i += 1024) dsh[i] = (i < N_ALL) ? 1e10f : -1.0f;
  for (int i = t; i < NCH; i += 1024) { cmaxLD[i] = 1e10f; bbLD[i] = bbox4[i]; }
  if (t == 0) { nact = 0; ncand = 0; nw = 0; }
  float cx = xsoa[0], cy = ysoa[0], cz = zsoa[0];
  if (t == 0) { axyz[0] = cx; axyz[1] = cy; axyz[2] = cz; }
  __syncthreads();

  for (int it = 1; it < NA; ++it) {
    // ---- phase T: test chunks (threads 0..312), build active list, fold inactive max ----
    if (wv < 5) {
      int c = t;
      bool act = false;
      float im = -1e30f;
      if (c < NCH) {
        float4 bb = bbLD[c];
        float cm = cmaxLD[c];
        unsigned pk = __float_as_uint(bb.w);
        const float s = 0.0009765625f;
        float hx = bb.x + (float)((pk & 1023u) + 1u) * s;
        float hy = bb.y + (float)(((pk >> 10) & 1023u) + 1u) * s;
        float hz = bb.z + (float)(((pk >> 20) & 1023u) + 1u) * s;
        float lx = fmaxf(fmaxf(bb.x - cx, cx - hx), 0.0f);
        float ly = fmaxf(fmaxf(bb.y - cy, cy - hy), 0.0f);
        float lz = fmaxf(fmaxf(bb.z - cz, cz - hz), 0.0f);
        float lb2 = (lx*lx + ly*ly) + lz*lz;      // same op tree as d -> d >= lb2 exactly
        act = lb2 < cm;
        if (!act) im = cm;
      }
      unsigned long long mk = __ballot(act);
      #pragma unroll
      for (int off = 1; off < 64; off <<= 1) im = fmaxf(im, __shfl_xor(im, off));
      if (lane == 0) wredT[wv] = im;
      int cnt_ = (int)__popcll(mk);
      int base = 0;
      if (lane == 0 && cnt_) base = atomicAdd(&nact, cnt_);
      base = __shfl(base, 0);
      if (act) actList[base + (int)__popcll(mk & ((1ull << lane) - 1ull))] = c;
    }
    __syncthreads();                                  // B1
    if (t == 0) { ncand = 0; nw = 0; }                // safe: cand/candB reads finished pre-B1
    // ---- phase U: update active chunks (interleaved over 16 waves) ----
    int nv = nact;
    float um = -1e30f;
    for (int ai = wv; ai < nv; ai += 16) {
      int c = actList[ai];
      int p = (c << 6) + lane;
      float4 f4 = pts4[p];
      float od = dsh[p];
      float dx = f4.x - cx, dy = f4.y - cy, dz = f4.z - cz;
      float d = (dx*dx + dy*dy) + dz*dz;              // exact reference tree
      float nd = fminf(od, d);
      dsh[p] = nd;
      float wm = nd;
      #pragma unroll
      for (int off = 1; off < 64; off <<= 1) wm = fmaxf(wm, __shfl_xor(wm, off));
      if (lane == 0) cmaxLD[c] = wm;
      um = fmaxf(um, wm);
    }
    if (lane == 0) wredU[wv] = um;
    __syncthreads();                                  // B2
    if (t == 0) nact = 0;                             // safe: nact reads finished pre-B2
    // ---- fold global max + collect candidate chunks ----
    float M = wredT[0];
    #pragma unroll
    for (int w = 1; w < 5; w++) M = fmaxf(M, wredT[w]);
    #pragma unroll
    for (int w = 0; w < 16; w++) M = fmaxf(M, wredU[w]);
    if (wv < 5 && t < NCH) {
      if (cmaxLD[t] == M) {
        int q = atomicAdd(&ncand, 1);
        if (q < 8) candC[q] = t;
      }
    }
    __syncthreads();                                  // B3
    // ---- wave 0: extract candidate points (coords + orig idx via one global dwordx4) ----
    if (wv == 0) {
      int nc = min(ncand, 8);
      for (int e = 0; e < nc; e++) {
        int c = candC[e];
        int p = (c << 6) + lane;
        if (dsh[p] == M) {
          float4 f4 = pts4[p];
          int q = atomicAdd(&nw, 1);
          if (q < 8) candB[q] = f4;
        }
      }
    }
    __syncthreads();                                  // B4
    // ---- all threads: pick lowest original index, becomes new center ----
    int n2 = min(nw, 8);
    unsigned bi = 0xFFFFFFFFu;
    float bx = cx, by = cy, bz = cz;
    for (int e = 0; e < n2; e++) {
      float4 g = candB[e];
      unsigned gi = (unsigned)__float_as_int(g.w);
      if (gi < bi) { bi = gi; bx = g.x; by = g.y; bz = g.z; }
    }
    cx = bx; cy = by; cz = bz;
    if (t == 0) { axyz[3*it] = cx; axyz[3*it+1] = cy; axyz[3*it+2] = cz; }
  }
}

// ---------------- ball query (wave per center): first K smallest indices with d2 < r2 ----------------
__global__ void sa_bq_kernel(const float* __restrict__ xyz,
                             const float* __restrict__ axyz,
                             int* __restrict__ nb) {
  #pragma clang fp contract(off)
  int wv = threadIdx.x >> 6, lane = threadIdx.x & 63;
  int a = blockIdx.x*4 + wv;
  float ax = axyz[3*a], ay = axyz[3*a+1], az = axyz[3*a+2];
  int cnt = 0, my = 0;
  for (int base = 0; base < N_ALL; base += 64) {
    int p = base + lane;
    bool in = false;
    if (p < N_ALL) {
      float dx = ax - xyz[3*p], dy = ay - xyz[3*p+1], dz = az - xyz[3*p+2];
      float d2 = (dx*dx + dy*dy) + dz*dz;
      in = d2 < 0.01f;
    }
    unsigned long long mask = __ballot(in);
    while (mask && cnt < SANS) {
      int b = __builtin_ctzll(mask);
      mask &= mask - 1;
      if (cnt == lane) my = base + b;
      cnt++;
    }
    if (cnt >= SANS) break;
  }
  int f0 = __shfl(my, 0);
  if (lane < SANS) nb[a*SANS + lane] = (lane < cnt) ? my : f0;
}

__global__ void det_bq_kernel(const float* __restrict__ pxyz,
                              int* __restrict__ nb) {
  #pragma clang fp contract(off)
  int wv = threadIdx.x >> 6, lane = threadIdx.x & 63;
  int i = blockIdx.x*4 + wv;
  float ax = pxyz[3*i], ay = pxyz[3*i+1], az = pxyz[3*i+2];
  int cnt = 0, my = 0;
  for (int base = 0; base < NPCD; base += 64) {
    int p = base + lane;
    bool in = false;
    if (p < NPCD) {
      float dx = ax - pxyz[3*p], dy = ay - pxyz[3*p+1], dz = az - pxyz[3*p+2];
      float d2 = (dx*dx + dy*dy) + dz*dz;
      in = d2 < 0.04f;
    }
    unsigned long long mask = __ballot(in);
    while (mask && cnt < NBK) {
      int b = __builtin_ctzll(mask);
      mask &= mask - 1;
      if (cnt == lane) my = base + b;
      cnt++;
    }
    if (cnt >= NBK) break;
  }
  int f0 = __shfl(my, 0);
  nb[i*NBK + lane] = (lane < cnt) ? my : f0;
}

// ---------------- SA: gather g(32x163) -> 3x MLP(128) -> maxpool, one anchor per block ----------------
__global__ void __launch_bounds__(128) sa_mlp_kernel(const float* __restrict__ xyz,
                                                     const float* __restrict__ feat,
                                                     const float* __restrict__ axyz,
                                                     const int* __restrict__ nb,
                                                     const float* __restrict__ W1p,
                                                     const float* __restrict__ b1,
                                                     const float* __restrict__ W2,
                                                     const float* __restrict__ b2,
                                                     const float* __restrict__ W3,
                                                     const float* __restrict__ b3,
                                                     float* __restrict__ sa_feat) {
  __shared__ float g[SANS*K1P];
  __shared__ float h1[SANS*HD];
  __shared__ int nbs[SANS];
  int a = blockIdx.x, tid = threadIdx.x;
  if (tid < SANS) nbs[tid] = nb[a*SANS + tid];
  float ax = axyz[3*a], ay = axyz[3*a+1], az = axyz[3*a+2];
  __syncthreads();
  for (int e = tid; e < SANS*K1P; e += 128) {
    int s = e / K1P, c = e - s*K1P;
    float v = 0.0f;
    int p = nbs[s];
    if (c < 3) {
      float pc  = xyz[3*p + c];
      float acx = (c == 0) ? ax : ((c == 1) ? ay : az);
      v = (pc - acx) / 0.1f;
    } else if (c < K1) {
      v = feat[p*CF + (c - 3)];
    }
    g[e] = v;
  }
  __syncthreads();
  const int o = tid;
  float acc[SANS];
  #pragma unroll
  for (int s = 0; s < SANS; s++) acc[s] = b1[o];
  for (int kc = 0; kc < 21; kc++) {
    const float4* wp = (const float4*)(W1p + o*K1P + kc*8);
    float4 w0 = wp[0], w1 = wp[1];
    #pragma unroll
    for (int s = 0; s < SANS; s++) {
      const float4* gp = (const float4*)(g + s*K1P + kc*8);
      float4 g0 = gp[0], g1 = gp[1];
      acc[s] += w0.x*g0.x + w0.y*g0.y + w0.z*g0.z + w0.w*g0.w
              + w1.x*g1.x + w1.y*g1.y + w1.z*g1.z + w1.w*g1.w;
    }
  }
  #pragma unroll
  for (int s = 0; s < SANS; s++) h1[s*HD + o] = fmaxf(acc[s], 0.0f);
  __syncthreads();
  #pragma unroll
  for (int s = 0; s < SANS; s++) acc[s] = b2[o];
  for (int kc = 0; kc < 16; kc++) {
    const float4* wp = (const float4*)(W2 + o*HD + kc*8);
    float4 w0 = wp[0], w1 = wp[1];
    #pragma unroll
    for (int s = 0; s < SANS; s++) {
      const float4* gp = (const float4*)(h1 + s*HD + kc*8);
      float4 g0 = gp[0], g1 = gp[1];
      acc[s] += w0.x*g0.x + w0.y*g0.y + w0.z*g0.z + w0.w*g0.w
              + w1.x*g1.x + w1.y*g1.y + w1.z*g1.z + w1.w*g1.w;
    }
  }
  float* h2 = g;
  #pragma unroll
  for (int s = 0; s < SANS; s++) h2[s*HD + o] = fmaxf(acc[s], 0.0f);
  __syncthreads();
  #pragma unroll
  for (int s = 0; s < SANS; s++) acc[s] = b3[o];
  for (int kc = 0; kc < 16; kc++) {
    const float4* wp = (const float4*)(W3 + o*HD + kc*8);
    float4 w0 = wp[0], w1 = wp[1];
    #pragma unroll
    for (int s = 0; s < SANS; s++) {
      const float4* gp = (const float4*)(h2 + s*HD + kc*8);
      float4 g0 = gp[0], g1 = gp[1];
      acc[s] += w0.x*g0.x + w0.y*g0.y + w0.z*g0.z + w0.w*g0.w
              + w1.x*g1.x + w1.y*g1.y + w1.z*g1.z + w1.w*g1.w;
    }
  }
  float m = 0.0f;
  #pragma unroll
  for (int s = 0; s < SANS; s++) m = fmaxf(m, fmaxf(acc[s], 0.0f));
  sa_feat[a*HD + o] = m;
}

// ---------------- 3-NN interp (first 5000 points only) + build F row [interp(128)|feat(160)] ----------------
#define INSERT3(v) { if ((v) < t0){ t2=t1; t1=t0; t0=(v);} \
                     else if ((v) < t1){ t2=t1; t1=(v);} \
                     else if ((v) < t2){ t2=(v);} }

__global__ void nn_interp_kernel(const float* __restrict__ xyz,
                                 const float* __restrict__ feat,
                                 const float* __restrict__ axyz,
                                 const float* __restrict__ sa_feat,
                                 float* __restrict__ F) {
  #pragma clang fp contract(off)
  int wv = threadIdx.x >> 6, lane = threadIdx.x & 63;
  int p = blockIdx.x*4 + wv;
  float px = xyz[3*p], py = xyz[3*p+1], pz = xyz[3*p+2];
  unsigned long long t0 = ~0ull, t1 = ~0ull, t2 = ~0ull;
  for (int j = 0; j < 64; j++) {
    int a = lane + (j << 6);
    float dx = px - axyz[3*a], dy = py - axyz[3*a+1], dz = pz - axyz[3*a+2];
    float d2 = (dx*dx + dy*dy) + dz*dz;
    unsigned long long pk = ((unsigned long long)__float_as_uint(d2) << 32) | (unsigned)a;
    INSERT3(pk);
  }
  #pragma unroll
  for (int off = 1; off < 64; off <<= 1) {
    unsigned long long b0 = __shfl_xor(t0, off);
    unsigned long long b1 = __shfl_xor(t1, off);
    unsigned long long b2 = __shfl_xor(t2, off);
    INSERT3(b0); INSERT3(b1); INSERT3(b2);
  }
  float d0 = __uint_as_float((unsigned)(t0 >> 32));
  float d1 = __uint_as_float((unsigned)(t1 >> 32));
  float d2v = __uint_as_float((unsigned)(t2 >> 32));
  int a0 = (int)(t0 & 0xFFFFFFFFull), a1 = (int)(t1 & 0xFFFFFFFFull), a2 = (int)(t2 & 0xFFFFFFFFull);
  float w0 = 1.0f/(d0 + 1e-8f), w1 = 1.0f/(d1 + 1e-8f), w2 = 1.0f/(d2v + 1e-8f);
  float wsum = w0 + w1 + w2;
  w0 /= wsum; w1 /= wsum; w2 /= wsum;
  const float* s0 = sa_feat + a0*HD;
  const float* s1 = sa_feat + a1*HD;
  const float* s2 = sa_feat + a2*HD;
  float* Fr = F + p*FPK;
  Fr[lane]      = w0*s0[lane]    + w1*s1[lane]    + w2*s2[lane];
  Fr[lane + 64] = w0*s0[lane+64] + w1*s1[lane+64] + w2*s2[lane+64];
  const float* fr = feat + p*CF;
  Fr[HD + lane]      = fr[lane];
  Fr[HD + lane + 64] = fr[lane + 64];
  if (lane < 32) Fr[HD + 128 + lane] = fr[128 + lane];
}

// ---------------- FP layer 1 ----------------
__global__ void __launch_bounds__(128) fp1_kernel(const float* __restrict__ F,
                                                  const float* __restrict__ W,
                                                  const float* __restrict__ b,
                                                  float* __restrict__ H) {
  __shared__ float A[32*FPK];
  int base = blockIdx.x*32, tid = threadIdx.x;
  for (int e = tid; e < 32*FPK; e += 128) {
    int r = e / FPK; int gr = base + r;
    A[e] = (gr < NPCD) ? F[gr*FPK + (e - r*FPK)] : 0.0f;
  }
  __syncthreads();
  const int o = tid;
  float acc[32];
  #pragma unroll
  for (int r = 0; r < 32; r++) acc[r] = b[o];
  for (int kc = 0; kc < 36; kc++) {
    const float4* wp = (const float4*)(W + o*FPK + kc*8);
    float4 w0 = wp[0], w1 = wp[1];
    #pragma unroll
    for (int r = 0; r < 32; r++) {
      const float4* ap = (const float4*)(A + r*FPK + kc*8);
      float4 a0 = ap[0], a1 = ap[1];
      acc[r] += w0.x*a0.x + w0.y*a0.y + w0.z*a0.z + w0.w*a0.w
              + w1.x*a1.x + w1.y*a1.y + w1.z*a1.z + w1.w*a1.w;
    }
  }
  #pragma unroll
  for (int r = 0; r < 32; r++) {
    int gr = base + r;
    if (gr < NPCD) H[gr*HD + o] = fmaxf(acc[r], 0.0f);
  }
}

// ---------------- FP layer 2 ----------------
__global__ void __launch_bounds__(256) fp2_kernel(const float* __restrict__ Hin,
                                                  const float* __restrict__ W,
                                                  const float* __restrict__ b,
                                                  float* __restrict__ fpf,
                                                  unsigned* __restrict__ gmax) {
  if (blockIdx.x == 0 && threadIdx.x == 0) *gmax = 0u;
  __shared__ float A[32*HD];
  int base = blockIdx.x*32, tid = threadIdx.x;
  for (int e = tid; e < 32*HD; e += 256) {
    int r = e >> 7; int gr = base + r;
    A[e] = (gr < NPCD) ? Hin[gr*HD + (e & 127)] : 0.0f;
  }
  __syncthreads();
  int o = tid & 31, rg = tid >> 5;
  float acc[4];
  #pragma unroll
  for (int j = 0; j < 4; j++) acc[j] = b[o];
  for (int kc = 0; kc < 16; kc++) {
    const float4* wp = (const float4*)(W + o*HD + kc*8);
    float4 w0 = wp[0], w1 = wp[1];
    #pragma unroll
    for (int j = 0; j < 4; j++) {
      int r = rg + (j << 3);
      const float4* ap = (const float4*)(A + r*HD + kc*8);
      float4 a0 = ap[0], a1 = ap[1];
      acc[j] += w0.x*a0.x + w0.y*a0.y + w0.z*a0.z + w0.w*a0.w
              + w1.x*a1.x + w1.y*a1.y + w1.z*a1.z + w1.w*a1.w;
    }
  }
  #pragma unroll
  for (int j = 0; j < 4; j++) {
    int gr = base + rg + (j << 3);
    if (gr < NPCD) fpf[gr*CPCD + o] = fmaxf(acc[j], 0.0f);
  }
}

// ---------------- global max of fp_feat ----------------
__global__ void gmax_kernel(const float* __restrict__ fpf, unsigned* __restrict__ gmax) {
  int id = blockIdx.x*256 + threadIdx.x;
  float m = (id < NPCD*CPCD) ? fpf[id] : 0.0f;
  #pragma unroll
  for (int off = 1; off < 64; off <<= 1) m = fmaxf(m, __shfl_xor(m, off));
  if ((threadIdx.x & 63) == 0) atomicMax(gmax, __float_as_uint(m));
}

// ---------------- detection scores (wave per point) ----------------
__global__ void det_score_kernel(const float* __restrict__ fpf,
                                 const int* __restrict__ nbd,
                                 const unsigned* __restrict__ gmax,
                                 float* __restrict__ outs) {
  int wv = threadIdx.x >> 6, lane = threadIdx.x & 63;
  int i = blockIdx.x*4 + wv;
  float g = __uint_as_float(*gmax);
  float scale = 1.0f / (g + 1e-6f);
  int c = lane & 31, h = lane >> 5;
  float sum = 0.0f;
  const int* nbr = nbd + i*NBK + h*32;
  for (int k = 0; k < 32; k++) {
    int idx = nbr[k];
    sum += fpf[idx*CPCD + c];
  }
  sum += __shfl_xor(sum, 32);
  float mean = (sum * scale) * 0.015625f;
  float fi = fpf[i*CPCD + c] * scale;
  float x = fi - mean;
  float lm = fmaxf(x, 0.0f) + log1pf(expf(-fabsf(x)));
  float dm = fi;
  #pragma unroll
  for (int off = 1; off < 64; off <<= 1) dm = fmaxf(dm, __shfl_xor(dm, off));
  float dw = fi / (1e-6f + dm);
  float pr = lm * dw;
  #pragma unroll
  for (int off = 1; off < 64; off <<= 1) pr = fmaxf(pr, __shfl_xor(pr, off));
  if (lane == 0) outs[i] = pr;
}

// ---------------- outputs ----------------
__global__ void vote_out_kernel(const float* __restrict__ pcd_xyz,
                                const float* __restrict__ fpf,
                                float* __restrict__ dout) {
  int id = blockIdx.x*256 + threadIdx.x;
  if (id < NPCD*3) dout[id] = pcd_xyz[id];
  int r = id - NPCD*3;
  if (r >= 0 && r < NPCD) {
    float ss = 0.0f;
    const float* fr = fpf + r*CPCD;
    #pragma unroll
    for (int cc = 0; cc < CPCD; cc++) ss += fr[cc]*fr[cc];
    float nrm = fmaxf(sqrtf(ss), 1e-12f);
    float* vf = dout + NPCD*3 + NPCD + r*CPCD;
    #pragma unroll
    for (int cc = 0; cc < CPCD; cc++) vf[cc] = fr[cc] / nrm;
  }
}

extern "C" void kernel_launch(void* const* d_in, const int* in_sizes, int n_in,
                              void* d_out, int out_size, void* d_ws, size_t ws_size,
                              hipStream_t stream) {
  const float* pcd_xyz      = (const float*)d_in[0];
  const float* pcd_features = (const float*)d_in[1];
  const float* rgb_xyz      = (const float*)d_in[2];
  const float* rgb_features = (const float*)d_in[3];
  const float* sa_W1 = (const float*)d_in[4];
  const float* sa_b1 = (const float*)d_in[5];
  const float* sa_W2 = (const float*)d_in[6];
  const float* sa_b2 = (const float*)d_in[7];
  const float* sa_W3 = (const float*)d_in[8];
  const float* sa_b3 = (const float*)d_in[9];
  const float* fp_W1 = (const float*)d_in[10];
  const float* fp_b1 = (const float*)d_in[11];
  const float* fp_W2 = (const float*)d_in[12];
  const float* fp_b2 = (const float*)d_in[13];
  float* out = (float*)d_out;

  float* xyz  = (float*)d_ws;            // 60000
  float* feat = xyz  + 60000;            // 3,200,000
  float* W1p  = feat + 3200000;          // 21,504
  float* axyz = W1p  + 21504;            // 12,288
  float* saf  = axyz + 12288;            // 524,288
  float* F    = saf  + 524288;           // 1,440,000
  float* Hb   = F    + 1440000;          // 640,000
  float* fpf  = Hb   + 640000;           // 160,000
  int*   nbsa = (int*)(fpf + 160000);    // 131,072
  int*   nbdet= nbsa + 131072;           // 320,000
  unsigned* gmaxp = (unsigned*)(nbdet + 320000);  // 1
  float* xsoa = (float*)(gmaxp + 1);     // 20480
  float* ysoa = xsoa + NSOA;             // 20480
  float* zsoa = ysoa + NSOA;             // 20480
  // FPS sort scratch aliases the F region (F is written only after fps completes)
  int*    cnt    = (int*)F;              // 512
  int*    ofs    = cnt + NCELL;          // 512
  int*    cellid = ofs + NCELL;          // 20000
  float4* pts4   = (float4*)(F + 21024); // 20032 float4 (16B-aligned: offset mult of 4)
  float4* bbox4  = (float4*)(F + 21024 + NPTS_PAD*4); // 313 float4

  prep_kernel<<<2048, 256, 0, stream>>>(pcd_xyz, pcd_features, rgb_xyz, rgb_features,
                                        sa_W1, xyz, feat, W1p, xsoa, ysoa, zsoa, cnt);
  cellcount_kernel<<<79, 256, 0, stream>>>(xsoa, ysoa, zsoa, cnt, cellid);
  cellscan_kernel<<<1, NCELL, 0, stream>>>(cnt, ofs);
  scatter_kernel<<<79, 256, 0, stream>>>(xsoa, ysoa, zsoa, cellid, ofs, pts4);
  bbox_kernel<<<NCH, 64, 0, stream>>>(pts4, bbox4);
  fps_kernel<<<1, 1024, 0, stream>>>(pts4, bbox4, xsoa, ysoa, zsoa, axyz);
  sa_bq_kernel<<<1024, 256, 0, stream>>>(xyz, axyz, nbsa);
  sa_mlp_kernel<<<4096, 128, 0, stream>>>(xyz, feat, axyz, nbsa, W1p, sa_b1,
                                          sa_W2, sa_b2, sa_W3, sa_b3, saf);
  nn_interp_kernel<<<1250, 256, 0, stream>>>(xyz, feat, axyz, saf, F);
  fp1_kernel<<<157, 128, 0, stream>>>(F, fp_W1, fp_b1, Hb);
  fp2_kernel<<<157, 256, 0, stream>>>(Hb, fp_W2, fp_b2, fpf, gmaxp);
  det_bq_kernel<<<1250, 256, 0, stream>>>(pcd_xyz, nbdet);
  gmax_kernel<<<625, 256, 0, stream>>>(fpf, gmaxp);
  det_score_kernel<<<1250, 256, 0, stream>>>(fpf, nbdet, gmaxp, out + NPCD*3);
  vote_out_kernel<<<79, 256, 0, stream>>>(pcd_xyz, fpf, out);
}